// Round 1
// baseline (564.579 us; speedup 1.0000x reference)
//
#include <hip/hip_runtime.h>

#define N_NODES 50000
#define E_EDGES 800000
#define NEG_SLOPE 0.2f

// ---------------- CSR build ----------------

__global__ void k_hist(const int* __restrict__ dst, int* __restrict__ deg) {
    int i = blockIdx.x * blockDim.x + threadIdx.x;
    if (i < E_EDGES) atomicAdd(&deg[dst[i]], 1);
}

__global__ void k_scanA(const int* __restrict__ deg, int* __restrict__ rowptr,
                        int* __restrict__ bsum, int n) {
    __shared__ int lds[256];
    int t = threadIdx.x;
    int i = blockIdx.x * 256 + t;
    int v = (i < n) ? deg[i] : 0;
    lds[t] = v;
    __syncthreads();
    for (int off = 1; off < 256; off <<= 1) {
        int u = (t >= off) ? lds[t - off] : 0;
        __syncthreads();
        lds[t] += u;
        __syncthreads();
    }
    if (i < n) rowptr[i + 1] = lds[t];       // inclusive partial
    if (t == 255) bsum[blockIdx.x] = lds[255];
}

__global__ void k_scanB(const int* __restrict__ bsum, int* __restrict__ boff, int nb) {
    __shared__ int lds[256];
    int t = threadIdx.x;
    int v = (t < nb) ? bsum[t] : 0;
    lds[t] = v;
    __syncthreads();
    for (int off = 1; off < 256; off <<= 1) {
        int u = (t >= off) ? lds[t - off] : 0;
        __syncthreads();
        lds[t] += u;
        __syncthreads();
    }
    if (t < nb) boff[t] = lds[t] - v;        // exclusive block offset
}

__global__ void k_scanC(const int* __restrict__ deg, const int* __restrict__ boff,
                        int* __restrict__ rowptr, int* __restrict__ cursor, int n) {
    int i = blockIdx.x * blockDim.x + threadIdx.x;
    if (i >= n) return;
    int v = rowptr[i + 1] + boff[i >> 8];
    rowptr[i + 1] = v;
    cursor[i] = v - deg[i];                  // start offset for node i
    if (i == 0) rowptr[0] = 0;
}

__global__ void k_scatter(const int* __restrict__ src, const int* __restrict__ dst,
                          int* __restrict__ cursor, int* __restrict__ csr_src) {
    int i = blockIdx.x * blockDim.x + threadIdx.x;
    if (i >= E_EDGES) return;
    int d = dst[i];
    int pos = atomicAdd(&cursor[d], 1);
    csr_src[pos] = src[i];
}

// ---------------- fp32 tiled GEMM: C[M,Nc] = A[M,K] * B[K,Nc] ----------------

__global__ __launch_bounds__(256) void gemm_f32(const float* __restrict__ A,
                                                const float* __restrict__ B,
                                                float* __restrict__ C,
                                                int M, int K, int Nc) {
    __shared__ float As[16][64];
    __shared__ float Bs[16][64];
    const int t = threadIdx.x;
    const int bm = blockIdx.x * 64;
    const int bn = blockIdx.y * 64;
    const int tm = (t & 15) * 4;
    const int tn = (t >> 4) * 4;
    const int arow = t >> 2;        // 0..63
    const int ak   = (t & 3) * 4;   // 0,4,8,12
    const int bk   = t >> 4;        // 0..15
    const int bcol = (t & 15) * 4;  // 0..60
    float acc[4][4] = {};
    for (int k0 = 0; k0 < K; k0 += 16) {
        float4 av = make_float4(0.f, 0.f, 0.f, 0.f);
        int grow = bm + arow;
        if (grow < M) av = *(const float4*)&A[(size_t)grow * K + k0 + ak];
        As[ak + 0][arow] = av.x;
        As[ak + 1][arow] = av.y;
        As[ak + 2][arow] = av.z;
        As[ak + 3][arow] = av.w;
        float4 bv = *(const float4*)&B[(size_t)(k0 + bk) * Nc + bn + bcol];
        *(float4*)&Bs[bk][bcol] = bv;
        __syncthreads();
#pragma unroll
        for (int k = 0; k < 16; ++k) {
            float a0 = As[k][tm + 0], a1 = As[k][tm + 1], a2 = As[k][tm + 2], a3 = As[k][tm + 3];
            float b0 = Bs[k][tn + 0], b1 = Bs[k][tn + 1], b2 = Bs[k][tn + 2], b3 = Bs[k][tn + 3];
            acc[0][0] += a0 * b0; acc[0][1] += a0 * b1; acc[0][2] += a0 * b2; acc[0][3] += a0 * b3;
            acc[1][0] += a1 * b0; acc[1][1] += a1 * b1; acc[1][2] += a1 * b2; acc[1][3] += a1 * b3;
            acc[2][0] += a2 * b0; acc[2][1] += a2 * b1; acc[2][2] += a2 * b2; acc[2][3] += a2 * b3;
            acc[3][0] += a3 * b0; acc[3][1] += a3 * b1; acc[3][2] += a3 * b2; acc[3][3] += a3 * b3;
        }
        __syncthreads();
    }
#pragma unroll
    for (int i = 0; i < 4; ++i) {
        int row = bm + tm + i;
        if (row < M) {
            float4 o = make_float4(acc[i][0], acc[i][1], acc[i][2], acc[i][3]);
            *(float4*)&C[(size_t)row * Nc + bn + tn] = o;
        }
    }
}

// ---------------- fused GATv2 edge-softmax + aggregation ----------------
// Layer 0: 4 heads x 64 dims. Wave per node; lane = head*16 + sub; each lane
// owns float4 of dims [head*64 + sub*4 .. +3]. Online softmax per 16-lane group.

__global__ __launch_bounds__(256) void gat_edge0(const float* __restrict__ feat,
                                                 const float* __restrict__ attn,
                                                 const int* __restrict__ rowptr,
                                                 const int* __restrict__ csr_src,
                                                 float* __restrict__ out) {
    const int lane = threadIdx.x & 63;
    const int node = blockIdx.x * 4 + (threadIdx.x >> 6);
    if (node >= N_NODES) return;
    const int dbase = ((lane >> 4) << 6) + (lane & 15) * 4;  // head*64 + sub*4
    const float4 a  = *(const float4*)&attn[dbase];
    const float4 fd = *(const float4*)&feat[(size_t)node * 256 + dbase];
    const int beg = rowptr[node], end = rowptr[node + 1];
    float m = -1e30f, s = 0.f;
    float ax = 0.f, ay = 0.f, az = 0.f, aw = 0.f;
    for (int j = beg; j < end; ++j) {
        int sn = csr_src[j];
        float4 fs = *(const float4*)&feat[(size_t)sn * 256 + dbase];
        float t0 = fs.x + fd.x; t0 = (t0 > 0.f) ? t0 : NEG_SLOPE * t0;
        float t1 = fs.y + fd.y; t1 = (t1 > 0.f) ? t1 : NEG_SLOPE * t1;
        float t2 = fs.z + fd.z; t2 = (t2 > 0.f) ? t2 : NEG_SLOPE * t2;
        float t3 = fs.w + fd.w; t3 = (t3 > 0.f) ? t3 : NEG_SLOPE * t3;
        float p = t0 * a.x + t1 * a.y + t2 * a.z + t3 * a.w;
        p += __shfl_xor(p, 1);
        p += __shfl_xor(p, 2);
        p += __shfl_xor(p, 4);
        p += __shfl_xor(p, 8);
        float nm = fmaxf(m, p);
        float c1 = __expf(m - nm);
        float c2 = __expf(p - nm);
        s  = s  * c1 + c2;
        ax = ax * c1 + c2 * fs.x;
        ay = ay * c1 + c2 * fs.y;
        az = az * c1 + c2 * fs.z;
        aw = aw * c1 + c2 * fs.w;
        m = nm;
    }
    float inv = (end > beg) ? (1.0f / s) : 0.f;
    float4 o;
    float v;
    v = ax * inv; o.x = (v > 0.f) ? v : (__expf(v) - 1.f);
    v = ay * inv; o.y = (v > 0.f) ? v : (__expf(v) - 1.f);
    v = az * inv; o.z = (v > 0.f) ? v : (__expf(v) - 1.f);
    v = aw * inv; o.w = (v > 0.f) ? v : (__expf(v) - 1.f);
    *(float4*)&out[(size_t)node * 256 + dbase] = o;
}

// Layer 1: 1 head x 64 dims, lane i owns dim i. Full-wave reduce (6 xor rounds).
// Output = acc/s (mean over the single head); no activation.

__global__ __launch_bounds__(256) void gat_edge1(const float* __restrict__ feat,
                                                 const float* __restrict__ attn,
                                                 const int* __restrict__ rowptr,
                                                 const int* __restrict__ csr_src,
                                                 float* __restrict__ out) {
    const int lane = threadIdx.x & 63;
    const int node = blockIdx.x * 4 + (threadIdx.x >> 6);
    if (node >= N_NODES) return;
    const float a  = attn[lane];
    const float fd = feat[(size_t)node * 64 + lane];
    const int beg = rowptr[node], end = rowptr[node + 1];
    float m = -1e30f, s = 0.f, acc = 0.f;
    for (int j = beg; j < end; ++j) {
        int sn = csr_src[j];
        float fs = feat[(size_t)sn * 64 + lane];
        float t = fs + fd; t = (t > 0.f) ? t : NEG_SLOPE * t;
        float p = t * a;
        p += __shfl_xor(p, 1);
        p += __shfl_xor(p, 2);
        p += __shfl_xor(p, 4);
        p += __shfl_xor(p, 8);
        p += __shfl_xor(p, 16);
        p += __shfl_xor(p, 32);
        float nm = fmaxf(m, p);
        float c1 = __expf(m - nm);
        float c2 = __expf(p - nm);
        s   = s   * c1 + c2;
        acc = acc * c1 + c2 * fs;
        m = nm;
    }
    float inv = (end > beg) ? (1.0f / s) : 0.f;
    out[(size_t)node * 64 + lane] = acc * inv;
}

// ---------------- launch ----------------

extern "C" void kernel_launch(void* const* d_in, const int* in_sizes, int n_in,
                              void* d_out, int out_size, void* d_ws, size_t ws_size,
                              hipStream_t stream) {
    const float* x     = (const float*)d_in[0];
    const float* W0    = (const float*)d_in[1];
    const float* attn0 = (const float*)d_in[2];
    const float* W1    = (const float*)d_in[3];
    const float* attn1 = (const float*)d_in[4];
    const int*   src0  = (const int*)d_in[5];
    const int*   dst0  = (const int*)d_in[6];
    const int*   src1  = (const int*)d_in[7];
    const int*   dst1  = (const int*)d_in[8];
    float* out = (float*)d_out;

    float* feat0 = (float*)d_ws;                       // N*256 f32
    float* h0    = feat0 + (size_t)N_NODES * 256;      // N*256 f32
    float* feat1 = feat0;                              // N*64, reuses feat0 region
    int* deg    = (int*)(h0 + (size_t)N_NODES * 256);  // N
    int* rowptr = deg + N_NODES;                       // N+1
    int* cursor = rowptr + N_NODES + 1;                // N
    int* bsum   = cursor + N_NODES;                    // 256
    int* boff   = bsum + 256;                          // 256
    int* csr    = boff + 256;                          // E

    const int nb = (N_NODES + 255) / 256;  // 196

    // ---- layer 0 ----
    gemm_f32<<<dim3((N_NODES + 63) / 64, 4), 256, 0, stream>>>(x, W0, feat0, N_NODES, 256, 256);

    hipMemsetAsync(deg, 0, N_NODES * sizeof(int), stream);
    k_hist<<<(E_EDGES + 255) / 256, 256, 0, stream>>>(dst0, deg);
    k_scanA<<<nb, 256, 0, stream>>>(deg, rowptr, bsum, N_NODES);
    k_scanB<<<1, 256, 0, stream>>>(bsum, boff, nb);
    k_scanC<<<nb, 256, 0, stream>>>(deg, boff, rowptr, cursor, N_NODES);
    k_scatter<<<(E_EDGES + 255) / 256, 256, 0, stream>>>(src0, dst0, cursor, csr);

    gat_edge0<<<(N_NODES + 3) / 4, 256, 0, stream>>>(feat0, attn0, rowptr, csr, h0);

    // ---- layer 1 ----
    gemm_f32<<<dim3((N_NODES + 63) / 64, 1), 256, 0, stream>>>(h0, W1, feat1, N_NODES, 256, 64);

    hipMemsetAsync(deg, 0, N_NODES * sizeof(int), stream);
    k_hist<<<(E_EDGES + 255) / 256, 256, 0, stream>>>(dst1, deg);
    k_scanA<<<nb, 256, 0, stream>>>(deg, rowptr, bsum, N_NODES);
    k_scanB<<<1, 256, 0, stream>>>(bsum, boff, nb);
    k_scanC<<<nb, 256, 0, stream>>>(deg, boff, rowptr, cursor, N_NODES);
    k_scatter<<<(E_EDGES + 255) / 256, 256, 0, stream>>>(src1, dst1, cursor, csr);

    gat_edge1<<<(N_NODES + 3) / 4, 256, 0, stream>>>(feat1, attn1, rowptr, csr, out);
}